// Round 8
// baseline (303.874 us; speedup 1.0000x reference)
//
#include <hip/hip_runtime.h>
#include <math.h>

// Problem constants
#define S_DIM 384
#define B_DIM 8
#define C_DIM 1024
#define H_DIM 16
#define M_DIM 1536
#define CC_DIM 64
#define ROWS  (S_DIM * B_DIM)      // 3072
#define N3C   (3 * C_DIM)          // 3072
#define NSPLIT 4

typedef unsigned short u16;
typedef short bf8v  __attribute__((ext_vector_type(8)));   // 8 bf16 (bit pattern)
typedef short bf4v  __attribute__((ext_vector_type(4)));   // 4 bf16
typedef u16   us8   __attribute__((ext_vector_type(8)));
typedef u16   us4   __attribute__((ext_vector_type(4)));
typedef float f4v   __attribute__((ext_vector_type(4)));

__device__ __forceinline__ u16 f2bf(float f) {
    unsigned u = __float_as_uint(f);
    u += 0x7fffu + ((u >> 16) & 1u);     // round-to-nearest-even
    return (u16)(u >> 16);
}
__device__ __forceinline__ float bf2f(u16 v) {
    return __uint_as_float(((unsigned)v) << 16);
}
#if __has_builtin(__builtin_amdgcn_exp2f)
#define EX2(x) __builtin_amdgcn_exp2f(x)
#else
#define EX2(x) __expf((x) * 0.69314718056f)
#endif
#define QSCALE (0.125f * 1.44269504f)    // 1/sqrt(64) * log2(e): softmax in exp2 domain

// MFMA 16x16x16 bf16 wrapper: builtin exists in the DEVICE pass (HW-verified
// rounds 4/6/7) but __has_builtin is false in the HOST pass — host needs a body.
__device__ __forceinline__ f4v mfma16x16x16bf16(bf4v a, bf4v b, f4v c) {
#if __has_builtin(__builtin_amdgcn_mfma_f32_16x16x16bf16_1k)
    return __builtin_amdgcn_mfma_f32_16x16x16bf16_1k(a, b, c, 0, 0, 0);
#else
    return c;   // host-pass placeholder; never executed on device
#endif
}

// async global->LDS, 16B per lane; lds dest must be wave-contiguous (base+lane*16)
__device__ __forceinline__ void gload16(const u16* g, u16* l) {
    __builtin_amdgcn_global_load_lds(
        (const __attribute__((address_space(1))) void*)g,
        (__attribute__((address_space(3))) void*)l, 16, 0, 0);
}

// ---------------------------------------------------------------------------
// prep_all: merged preps, restructured for ILP (fat blocks, unrolled
// independent iterations). Block ranges:
//   [0,768)      prep_a  : Abf = bf16(x+pe), 4096 elts/block
//   [768,1536)   wqkv^T  : 64x64 fp32 transpose tiles
//   [1536,1792)  wout^T  : 64x64 tiles
//   [1792,3328)  mk      : 128 rows/block, 8 indep iters/thread
//   [3328,4864)  mv      : 2 transpose tiles/block (2x LDS)
// ---------------------------------------------------------------------------
__device__ __forceinline__ void tr64(const float* __restrict__ in, u16* __restrict__ out,
                                     int R, int Cc, int r0, int c0, int tid, float* sm) {
    #pragma unroll
    for (int i = 0; i < 16; i++) {
        int r = i * 4 + (tid >> 6), c = tid & 63;
        sm[r * 65 + c] = in[(size_t)(r0 + r) * Cc + c0 + c];
    }
    __syncthreads();
    #pragma unroll
    for (int i = 0; i < 16; i++) {
        int cw = i * 4 + (tid >> 6), rw = tid & 63;
        out[(size_t)(c0 + cw) * R + r0 + rw] = f2bf(sm[rw * 65 + cw]);
    }
}

__global__ __launch_bounds__(256) void prep_all(
    const float* __restrict__ x, const float* __restrict__ pe, u16* __restrict__ Abf,
    const float* __restrict__ wqkv, u16* __restrict__ Wqkvt,
    const float* __restrict__ wout, u16* __restrict__ Woutt,
    const float* __restrict__ mk, u16* __restrict__ mk_bf,
    const float* __restrict__ mv, u16* __restrict__ mv_t)
{
    __shared__ float sm[2][64 * 65];
    const int bid = blockIdx.x, tid = threadIdx.x;

    if (bid < 768) {                        // prep_a: 4 indep float4-pairs/thread
        size_t base = (size_t)bid * 4096 + tid * 4;
        #pragma unroll
        for (int j = 0; j < 4; j++) {
            size_t i = base + j * 1024;
            float4 xv = *(const float4*)(x + i);
            float4 pv = *(const float4*)(pe + i);
            us4 o;
            o[0] = f2bf(xv.x + pv.x); o[1] = f2bf(xv.y + pv.y);
            o[2] = f2bf(xv.z + pv.z); o[3] = f2bf(xv.w + pv.w);
            *(us4*)(Abf + i) = o;
        }
    } else if (bid < 1536) {                // wqkv^T: 16 x 48 tiles of 64x64
        int b2 = bid - 768;
        tr64(wqkv, Wqkvt, C_DIM, N3C, (b2 / 48) * 64, (b2 % 48) * 64, tid, sm[0]);
    } else if (bid < 1792) {                // wout^T: 16 x 16 tiles
        int b3 = bid - 1536;
        tr64(wout, Woutt, C_DIM, C_DIM, (b3 / 16) * 64, (b3 % 16) * 64, tid, sm[0]);
    } else if (bid < 3328) {                // mk: 128 rows/block, 8 iters
        int b4 = bid - 1792;
        int c4 = (tid & 15) * 4;
        #pragma unroll
        for (int j = 0; j < 8; j++) {
            int R = b4 * 128 + j * 16 + (tid >> 4);
            int t = R >> 7, bhh = R & 127;
            float4 v = *(const float4*)&mk[(size_t)R * 64 + c4];
            us4 o;
            o[0] = f2bf(v.x); o[1] = f2bf(v.y); o[2] = f2bf(v.z); o[3] = f2bf(v.w);
            *(us4*)&mk_bf[((size_t)bhh * M_DIM + t) * 64 + c4] = o;
        }
    } else {                                // mv: 2 tiles/block -> [bh][cc][t]
        int b5 = bid - 3328;
        int bh = b5 & 127, t0 = (b5 >> 7) * 128;
        #pragma unroll
        for (int p = 0; p < 2; p++)
            #pragma unroll
            for (int i = 0; i < 16; i++) {
                int r = i * 4 + (tid >> 6), c = tid & 63;
                sm[p][r * 65 + c] = mv[((size_t)(t0 + p * 64 + r) * 128 + bh) * 64 + c];
            }
        __syncthreads();
        #pragma unroll
        for (int p = 0; p < 2; p++)
            #pragma unroll
            for (int i = 0; i < 16; i++) {
                int cc = i * 4 + (tid >> 6), tw = tid & 63;
                mv_t[((size_t)bh * 64 + cc) * M_DIM + t0 + p * 64 + tw] = f2bf(sm[p][tw * 65 + cc]);
            }
    }
}

// ---------------------------------------------------------------------------
// prep_vwt: Vw[bh][s][cc] bf16 -> Vwt[bh][cc][s] bf16
// ---------------------------------------------------------------------------
__global__ __launch_bounds__(256) void prep_vwt(
    const u16* __restrict__ Vw, u16* __restrict__ Vwt)
{
    __shared__ u16 tile[64][66];
    const int tid = threadIdx.x;
    const int bh = blockIdx.x & 127;
    const int t0 = (blockIdx.x >> 7) * 64;
    #pragma unroll
    for (int i = 0; i < 16; i++) {
        int r = i * 4 + (tid >> 6), c = tid & 63;
        tile[r][c] = Vw[((size_t)bh * S_DIM + t0 + r) * 64 + c];
    }
    __syncthreads();
    #pragma unroll
    for (int i = 0; i < 16; i++) {
        int cc = i * 4 + (tid >> 6), tw = tid & 63;
        Vwt[((size_t)bh * 64 + cc) * S_DIM + t0 + tw] = tile[tw][cc];
    }
}

// ---------------------------------------------------------------------------
// qkv GEMM: 128x64 tiles, BK=64, DOUBLE-BUFFERED XOR-swizzled DMA staging.
// One barrier per K-iter: barrier -> issue next-buffer DMA -> compute current.
// The vmcnt(0) drain at the barrier then waits on loads issued a full
// MFMA-phase earlier (mostly complete) instead of just-issued ones.
// ---------------------------------------------------------------------------
__global__ __launch_bounds__(256) void qkv_gemm(
    const u16* __restrict__ Abf, const u16* __restrict__ Wt,
    const float* __restrict__ bias,
    u16* __restrict__ Qw, u16* __restrict__ Kw, u16* __restrict__ Vw)
{
    __shared__ u16 As[2 * 128 * 64];
    __shared__ u16 Bs[2 * 64 * 64];
    const int tid = threadIdx.x;
    const int lane = tid & 63, w = tid >> 6;
    const int lr = lane & 15, quad = lane >> 4;
    const int wm = w >> 1, wn = w & 1;
    const int row0 = blockIdx.y * 128, col0 = blockIdx.x * 64;

    auto stage = [&](int bu, int k0) {
        u16* Ad = &As[bu * 128 * 64];
        u16* Bd = &Bs[bu * 64 * 64];
        #pragma unroll
        for (int j = 0; j < 4; j++) {
            int idx = j * 256 + tid;
            int r = idx >> 3, c = (idx & 7) ^ (r & 7);
            gload16(&Abf[(size_t)(row0 + r) * C_DIM + k0 + c * 8], &Ad[idx * 8]);
        }
        #pragma unroll
        for (int j = 0; j < 2; j++) {
            int idx = j * 256 + tid;
            int r = idx >> 3, c = (idx & 7) ^ (r & 7);
            gload16(&Wt[(size_t)(col0 + r) * C_DIM + k0 + c * 8], &Bd[idx * 8]);
        }
    };

    f4v acc[4][2];
    #pragma unroll
    for (int i = 0; i < 4; i++)
        #pragma unroll
        for (int j = 0; j < 2; j++)
            acc[i][j] = (f4v){0.f, 0.f, 0.f, 0.f};

    stage(0, 0);
    for (int ki = 0; ki < 16; ki++) {
        __syncthreads();                       // drains current buffer's DMA
        if (ki < 15) stage((ki + 1) & 1, (ki + 1) * 64);
        const u16* Ab = &As[(ki & 1) * 128 * 64];
        const u16* Bb = &Bs[(ki & 1) * 64 * 64];
        #pragma unroll
        for (int kh = 0; kh < 2; kh++) {
            bf8v a[4], b[2];
            #pragma unroll
            for (int mi = 0; mi < 4; mi++) {
                int row = wm * 64 + mi * 16 + lr;
                int p = (kh * 4 + quad) ^ (lr & 7);
                a[mi] = *(const bf8v*)&Ab[row * 64 + p * 8];
            }
            #pragma unroll
            for (int nj = 0; nj < 2; nj++) {
                int row = wn * 32 + nj * 16 + lr;
                int p = (kh * 4 + quad) ^ (lr & 7);
                b[nj] = *(const bf8v*)&Bb[row * 64 + p * 8];
            }
            #pragma unroll
            for (int mi = 0; mi < 4; mi++)
                #pragma unroll
                for (int nj = 0; nj < 2; nj++)
                    acc[mi][nj] = __builtin_amdgcn_mfma_f32_16x16x32_bf16(a[mi], b[nj], acc[mi][nj], 0, 0, 0);
        }
    }

    #pragma unroll
    for (int nj = 0; nj < 2; nj++) {
        int col = col0 + wn * 32 + nj * 16 + lr;
        float bv = bias[col];
        int which = col >> 10;
        int h = (col >> 6) & 15, cc = col & 63;
        #pragma unroll
        for (int mi = 0; mi < 4; mi++) {
            #pragma unroll
            for (int reg = 0; reg < 4; reg++) {
                int rg = row0 + wm * 64 + mi * 16 + quad * 4 + reg;
                int s = rg >> 3, bb = rg & 7;
                float v = acc[mi][nj][reg] + bv;
                size_t dst = ((size_t)((bb * 16 + h) * S_DIM) + s) * 64 + cc;
                if (which == 0)      Qw[dst] = f2bf(v * QSCALE);
                else if (which == 1) Kw[dst] = f2bf(v);
                else                 Vw[dst] = f2bf(v);
            }
        }
    }
}

// ---------------------------------------------------------------------------
// attn_split: 64-key chunks, DOUBLE-BUFFERED DMA staging (XOR-swizzled),
// P in registers, exp2 softmax, wave-uniform mask skip, one barrier/chunk.
// ---------------------------------------------------------------------------
__global__ __launch_bounds__(256) void attn_split(
    const u16* __restrict__ Qw, const u16* __restrict__ Kw,
    const u16* __restrict__ mk_bf, const u16* __restrict__ Vwt,
    const u16* __restrict__ mv_t, const unsigned char* __restrict__ terminal,
    const int* __restrict__ mem_len, u16* __restrict__ Op, float* __restrict__ ml)
{
    __shared__ u16 Ks[2 * 64 * 64];   // [t][cc], chunk-swizzled
    __shared__ u16 Vs[2 * 64 * 64];   // [cc][t], chunk-swizzled

    const int tid = threadIdx.x;
    const int lane = tid & 63, w = tid >> 6;
    const int lr = lane & 15, quad = lane >> 4, q8 = quad * 8;
    const int bid = blockIdx.x;
    const int split = bid & (NSPLIT - 1);
    const int g = bid / NSPLIT;                     // bhsc
    const int b = g & 7, h = (g >> 3) & 15, sc = g >> 7;
    const int bh = b * 16 + h, sq0 = sc * 64;
    const int L = terminal[b] ? 0 : mem_len[b];
    const int qrow = sq0 + w * 16 + lr;

    // Q as B-fragment (pre-scaled by QSCALE in qkv epilogue)
    const u16* qbase = Qw + ((size_t)bh * S_DIM + sq0 + w * 16 + lr) * 64;
    bf8v qf0 = *(const bf8v*)&qbase[q8];
    bf8v qf1 = *(const bf8v*)&qbase[32 + q8];

    f4v O[4];
    #pragma unroll
    for (int nj = 0; nj < 4; nj++) O[nj] = (f4v){0.f, 0.f, 0.f, 0.f};
    float m_i = -1e30f, l_i = 0.0f;

    const int memChunks = (L + 63) >> 6;
    const int total = memChunks + sc + 1;
    const int lo = (split * total) / NSPLIT;
    const int hi = ((split + 1) * total) / NSPLIT;

    const f4v zero = (f4v){0.f, 0.f, 0.f, 0.f};

    auto stageCh = [&](int bu, int ch) {
        const bool isM = (ch < memChunks);
        const int tl = isM ? ch * 64 : (ch - memChunks) * 64;
        const u16* kb = isM ? mk_bf + ((size_t)bh * M_DIM + tl) * 64
                            : Kw + ((size_t)bh * S_DIM + tl) * 64;
        const u16* vb; size_t vstr;
        if (isM) { vb = mv_t + (size_t)bh * 64 * M_DIM + tl; vstr = M_DIM; }
        else     { vb = Vwt + (size_t)bh * 64 * S_DIM + tl; vstr = S_DIM; }
        u16* Kd = &Ks[bu * 64 * 64];
        u16* Vd = &Vs[bu * 64 * 64];
        #pragma unroll
        for (int j = 0; j < 2; j++) {
            int idx = j * 256 + tid;
            int r = idx >> 3, c = (idx & 7) ^ (r & 7);
            gload16(kb + (size_t)r * 64 + c * 8, &Kd[idx * 8]);
        }
        #pragma unroll
        for (int j = 0; j < 2; j++) {
            int idx = j * 256 + tid;
            int cc = idx >> 3, c = (idx & 7) ^ (cc & 7);
            gload16(vb + (size_t)cc * vstr + c * 8, &Vd[idx * 8]);
        }
    };

    if (lo < hi) stageCh(0, lo);

    for (int ch = lo; ch < hi; ch++) {
        const int bu = (ch - lo) & 1;
        const bool isMem = (ch < memChunks);
        const int tloc = isMem ? ch * 64 : (ch - memChunks) * 64;

        __syncthreads();                       // drains buffer bu's DMA
        if (ch + 1 < hi) stageCh(bu ^ 1, ch + 1);

        const u16* Kb = &Ks[bu * 64 * 64];
        const u16* Vb = &Vs[bu * 64 * 64];

        // S^T tiles: sv[tt] covers t = tloc + tt*16 + quad*4 + reg, q = lane&15
        f4v sv[4];
        #pragma unroll
        for (int tt = 0; tt < 4; tt++) {
            int row = tt * 16 + lr;
            int p0 = quad ^ (lr & 7), p1 = (4 + quad) ^ (lr & 7);
            bf8v k0 = *(const bf8v*)&Kb[row * 64 + p0 * 8];
            bf8v k1 = *(const bf8v*)&Kb[row * 64 + p1 * 8];
            sv[tt] = __builtin_amdgcn_mfma_f32_16x16x32_bf16(k0, qf0, zero, 0, 0, 0);
            sv[tt] = __builtin_amdgcn_mfma_f32_16x16x32_bf16(k1, qf1, sv[tt], 0, 0, 0);
        }

        // Mask — wave-uniform skip (only boundary/diagonal chunks pay)
        if (isMem) {
            if (tloc + 64 > L) {
                #pragma unroll
                for (int tt = 0; tt < 4; tt++)
                    #pragma unroll
                    for (int reg = 0; reg < 4; reg++) {
                        int t = tloc + tt * 16 + quad * 4 + reg;
                        if (t >= L) sv[tt][reg] = -1e30f;
                    }
            }
        } else {
            if (tloc + 63 > sq0 + w * 16) {
                #pragma unroll
                for (int tt = 0; tt < 4; tt++)
                    #pragma unroll
                    for (int reg = 0; reg < 4; reg++) {
                        int t = tloc + tt * 16 + quad * 4 + reg;
                        if (t > qrow) sv[tt][reg] = -1e30f;
                    }
            }
        }

        // Online softmax in exp2 domain; reduce across lanes q, q+16, q+32, q+48
        float rowmax = fmaxf(fmaxf(sv[0][0], sv[0][1]), fmaxf(sv[0][2], sv[0][3]));
        #pragma unroll
        for (int tt = 1; tt < 4; tt++)
            rowmax = fmaxf(rowmax, fmaxf(fmaxf(sv[tt][0], sv[tt][1]),
                                         fmaxf(sv[tt][2], sv[tt][3])));
        rowmax = fmaxf(rowmax, __shfl_xor(rowmax, 16));
        rowmax = fmaxf(rowmax, __shfl_xor(rowmax, 32));
        float mnew = fmaxf(m_i, rowmax);
        float alpha = EX2(m_i - mnew);
        m_i = mnew;
        float sum = 0.0f;
        bf4v pf[4];
        #pragma unroll
        for (int tt = 0; tt < 4; tt++) {
            #pragma unroll
            for (int reg = 0; reg < 4; reg++) {
                float p = EX2(sv[tt][reg] - mnew);
                sum += p;
                pf[tt][reg] = (short)f2bf(p);
            }
        }
        sum += __shfl_xor(sum, 16);
        sum += __shfl_xor(sum, 32);
        l_i = l_i * alpha + sum;

        // Realign alpha to O-tile rows (O row q' = quad*4+reg; alpha at lane q')
        float alphaR[4];
        #pragma unroll
        for (int reg = 0; reg < 4; reg++)
            alphaR[reg] = __shfl(alpha, quad * 4 + reg);
        #pragma unroll
        for (int nj = 0; nj < 4; nj++)
            #pragma unroll
            for (int reg = 0; reg < 4; reg++)
                O[nj][reg] *= alphaR[reg];

        // PV: A = P (regs), B = V from Vs[cc][t] (de-swizzled bf4v reads)
        #pragma unroll
        for (int tt = 0; tt < 4; tt++) {
            #pragma unroll
            for (int nj = 0; nj < 4; nj++) {
                int cc = nj * 16 + lr;
                int c = (tt * 2 + (quad >> 1)) ^ (lr & 7);
                bf4v vf = *(const bf4v*)&Vb[cc * 64 + c * 8 + (quad & 1) * 4];
                O[nj] = mfma16x16x16bf16(pf[tt], vf, O[nj]);
            }
        }
    }

    // Write partials
    const size_t pbase = (size_t)(g * NSPLIT + split) * 64;
    if (quad == 0) {
        int row = w * 16 + lr;
        float2 mlv = {m_i, l_i};
        *(float2*)&ml[(pbase + row) * 2] = mlv;
    }
    #pragma unroll
    for (int reg = 0; reg < 4; reg++) {
        int row = w * 16 + quad * 4 + reg;
        #pragma unroll
        for (int nj = 0; nj < 4; nj++)
            Op[(pbase + row) * 64 + nj * 16 + lr] = f2bf(O[nj][reg]);
    }
}

// ---------------------------------------------------------------------------
// attn_combine: merge NSPLIT partials -> Obf[row=s*8+b][h*64+cc] bf16
// ---------------------------------------------------------------------------
__global__ __launch_bounds__(256) void attn_combine(
    const u16* __restrict__ Op, const float* __restrict__ ml, u16* __restrict__ Obf)
{
    const int g = blockIdx.x;                       // bhsc
    const int b = g & 7, h = (g >> 3) & 15, sc = g >> 7;
    const int tid = threadIdx.x;
    const int row = tid >> 2, c0 = (tid & 3) * 16;

    float m[NSPLIT], lv[NSPLIT];
    #pragma unroll
    for (int j = 0; j < NSPLIT; j++) {
        size_t base = (size_t)(g * NSPLIT + j) * 64 + row;
        m[j]  = ml[base * 2];
        lv[j] = ml[base * 2 + 1];
    }
    float mstar = m[0];
    #pragma unroll
    for (int j = 1; j < NSPLIT; j++) mstar = fmaxf(mstar, m[j]);
    float sc_j[NSPLIT], l = 0.0f;
    #pragma unroll
    for (int j = 0; j < NSPLIT; j++) {
        sc_j[j] = EX2(m[j] - mstar);                // exp2 domain
        l += sc_j[j] * lv[j];
    }
    float inv = 1.0f / l;

    float o[16];
    #pragma unroll
    for (int c = 0; c < 16; c++) o[c] = 0.0f;
    #pragma unroll
    for (int j = 0; j < NSPLIT; j++) {
        const u16* src = &Op[((size_t)(g * NSPLIT + j) * 64 + row) * 64 + c0];
        us8 v0 = *(const us8*)src;
        us8 v1 = *(const us8*)(src + 8);
        #pragma unroll
        for (int c = 0; c < 8; c++) {
            o[c]     += sc_j[j] * bf2f(v0[c]);
            o[c + 8] += sc_j[j] * bf2f(v1[c]);
        }
    }
    int s = sc * 64 + row;
    size_t dst = ((size_t)s * 8 + b) * C_DIM + h * 64 + c0;
    us8 w0, w1;
    #pragma unroll
    for (int c = 0; c < 8; c++) {
        w0[c] = f2bf(o[c] * inv);
        w1[c] = f2bf(o[c + 8] * inv);
    }
    *(us8*)&Obf[dst] = w0;
    *(us8*)&Obf[dst + 8] = w1;
}

// ---------------------------------------------------------------------------
// proj GEMM: 128x64 tile, BK=64, DOUBLE-BUFFERED swizzled DMA staging.
// ---------------------------------------------------------------------------
__global__ __launch_bounds__(256) void proj_gemm(
    const u16* __restrict__ Abf, const u16* __restrict__ Wt,
    const float* __restrict__ bias, float* __restrict__ out)
{
    __shared__ u16 As[2 * 128 * 64];
    __shared__ u16 Bs[2 * 64 * 64];
    const int tid = threadIdx.x;
    const int lane = tid & 63, w = tid >> 6;
    const int lr = lane & 15, quad = lane >> 4;
    const int wm = w >> 1, wn = w & 1;
    const int row0 = blockIdx.y * 128, col0 = blockIdx.x * 64;

    auto stage = [&](int bu, int k0) {
        u16* Ad = &As[bu * 128 * 64];
        u16* Bd = &Bs[bu * 64 * 64];
        #pragma unroll
        for (int j = 0; j < 4; j++) {
            int idx = j * 256 + tid;
            int r = idx >> 3, c = (idx & 7) ^ (r & 7);
            gload16(&Abf[(size_t)(row0 + r) * C_DIM + k0 + c * 8], &Ad[idx * 8]);
        }
        #pragma unroll
        for (int j = 0; j < 2; j++) {
            int idx = j * 256 + tid;
            int r = idx >> 3, c = (idx & 7) ^ (r & 7);
            gload16(&Wt[(size_t)(col0 + r) * C_DIM + k0 + c * 8], &Bd[idx * 8]);
        }
    };

    f4v acc[4][2];
    #pragma unroll
    for (int i = 0; i < 4; i++)
        #pragma unroll
        for (int j = 0; j < 2; j++)
            acc[i][j] = (f4v){0.f, 0.f, 0.f, 0.f};

    stage(0, 0);
    for (int ki = 0; ki < 16; ki++) {
        __syncthreads();
        if (ki < 15) stage((ki + 1) & 1, (ki + 1) * 64);
        const u16* Ab = &As[(ki & 1) * 128 * 64];
        const u16* Bb = &Bs[(ki & 1) * 64 * 64];
        #pragma unroll
        for (int kh = 0; kh < 2; kh++) {
            bf8v a[4], b[2];
            #pragma unroll
            for (int mi = 0; mi < 4; mi++) {
                int row = wm * 64 + mi * 16 + lr;
                int p = (kh * 4 + quad) ^ (lr & 7);
                a[mi] = *(const bf8v*)&Ab[row * 64 + p * 8];
            }
            #pragma unroll
            for (int nj = 0; nj < 2; nj++) {
                int row = wn * 32 + nj * 16 + lr;
                int p = (kh * 4 + quad) ^ (lr & 7);
                b[nj] = *(const bf8v*)&Bb[row * 64 + p * 8];
            }
            #pragma unroll
            for (int mi = 0; mi < 4; mi++)
                #pragma unroll
                for (int nj = 0; nj < 2; nj++)
                    acc[mi][nj] = __builtin_amdgcn_mfma_f32_16x16x32_bf16(a[mi], b[nj], acc[mi][nj], 0, 0, 0);
        }
    }

    #pragma unroll
    for (int nj = 0; nj < 2; nj++) {
        int col = col0 + wn * 32 + nj * 16 + lr;
        float bv = bias[col];
        #pragma unroll
        for (int mi = 0; mi < 4; mi++) {
            #pragma unroll
            for (int reg = 0; reg < 4; reg++) {
                int rg = row0 + wm * 64 + mi * 16 + quad * 4 + reg;
                out[(size_t)rg * C_DIM + col] = acc[mi][nj][reg] + bv;
            }
        }
    }
}

// ---------------------------------------------------------------------------
extern "C" void kernel_launch(void* const* d_in, const int* in_sizes, int n_in,
                              void* d_out, int out_size, void* d_ws, size_t ws_size,
                              hipStream_t stream) {
    const float* x    = (const float*)d_in[0];
    const float* pe   = (const float*)d_in[1];
    const float* mk   = (const float*)d_in[2];
    const float* mv   = (const float*)d_in[3];
    const float* wqkv = (const float*)d_in[4];
    const float* bqkv = (const float*)d_in[5];
    const float* wout = (const float*)d_in[6];
    const float* bout = (const float*)d_in[7];
    const unsigned char* term = (const unsigned char*)d_in[8];
    // d_in[9] content_mask (causal, analytic), d_in[10] padding_mask (all False)
    const int* mem_len = (const int*)d_in[11];

    char* ws = (char*)d_ws;
    u16* Abf   = (u16*)(ws + 0);          // 6291456 B  (Obf aliases after qkv)
    u16* Obf   = (u16*)(ws + 0);
    u16* Wqkvt = (u16*)(ws + 6291456);    // 6291456 B  (Vwt aliases after qkv)
    u16* Vwt   = (u16*)(ws + 6291456);
    u16* Woutt = (u16*)(ws + 12582912);   // 2097152 B
    u16* mk_bf = (u16*)(ws + 14680064);   // 25165824 B
    u16* mv_t  = (u16*)(ws + 39845888);   // 25165824 B
    u16* Qw    = (u16*)(ws + 65011712);   // 6291456 B
    u16* Kw    = (u16*)(ws + 71303168);   // 6291456 B
    u16* Vw    = (u16*)(ws + 77594624);   // 6291456 B
    u16* Op    = (u16*)(ws + 83886080);   // 25165824 B (768*4*64*64 bf16)
    float* ml  = (float*)(ws + 109051904);// 1572864 B  end 110624768

    float* out = (float*)d_out;

    prep_all<<<4864, 256, 0, stream>>>(x, pe, Abf, wqkv, Wqkvt, wout, Woutt,
                                       mk, mk_bf, mv, mv_t);

    qkv_gemm<<<dim3(N3C / 64, ROWS / 128), 256, 0, stream>>>(
        Abf, Wqkvt, bqkv, Qw, Kw, Vw);

    prep_vwt<<<(S_DIM / 64) * 128, 256, 0, stream>>>(Vw, Vwt);

    attn_split<<<B_DIM * H_DIM * (S_DIM / 64) * NSPLIT, 256, 0, stream>>>(
        Qw, Kw, mk_bf, Vwt, mv_t, term, mem_len, Op, ml);

    attn_combine<<<B_DIM * H_DIM * (S_DIM / 64), 256, 0, stream>>>(Op, ml, Obf);

    proj_gemm<<<dim3(C_DIM / 64, ROWS / 128), 256, 0, stream>>>(
        Obf, Woutt, bout, out);
}

// Round 9
// 303.226 us; speedup vs baseline: 1.0021x; 1.0021x over previous
//
#include <hip/hip_runtime.h>
#include <math.h>

// Problem constants
#define S_DIM 384
#define B_DIM 8
#define C_DIM 1024
#define H_DIM 16
#define M_DIM 1536
#define CC_DIM 64
#define ROWS  (S_DIM * B_DIM)      // 3072
#define N3C   (3 * C_DIM)          // 3072
#define NSPLIT 4

typedef unsigned short u16;
typedef short bf8v  __attribute__((ext_vector_type(8)));   // 8 bf16 (bit pattern)
typedef short bf4v  __attribute__((ext_vector_type(4)));   // 4 bf16
typedef u16   us8   __attribute__((ext_vector_type(8)));
typedef u16   us4   __attribute__((ext_vector_type(4)));
typedef float f4v   __attribute__((ext_vector_type(4)));

__device__ __forceinline__ u16 f2bf(float f) {
    unsigned u = __float_as_uint(f);
    u += 0x7fffu + ((u >> 16) & 1u);     // round-to-nearest-even
    return (u16)(u >> 16);
}
__device__ __forceinline__ float bf2f(u16 v) {
    return __uint_as_float(((unsigned)v) << 16);
}
#if __has_builtin(__builtin_amdgcn_exp2f)
#define EX2(x) __builtin_amdgcn_exp2f(x)
#else
#define EX2(x) __expf((x) * 0.69314718056f)
#endif
#define QSCALE (0.125f * 1.44269504f)    // 1/sqrt(64) * log2(e): softmax in exp2 domain

// MFMA 16x16x16 bf16 wrapper: builtin exists in the DEVICE pass (HW-verified
// rounds 4/6/7) but __has_builtin is false in the HOST pass — host needs a body.
__device__ __forceinline__ f4v mfma16x16x16bf16(bf4v a, bf4v b, f4v c) {
#if __has_builtin(__builtin_amdgcn_mfma_f32_16x16x16bf16_1k)
    return __builtin_amdgcn_mfma_f32_16x16x16bf16_1k(a, b, c, 0, 0, 0);
#else
    return c;   // host-pass placeholder; never executed on device
#endif
}

// async global->LDS, 16B per lane; lds dest must be wave-contiguous (base+lane*16)
__device__ __forceinline__ void gload16(const u16* g, u16* l) {
    __builtin_amdgcn_global_load_lds(
        (const __attribute__((address_space(1))) void*)g,
        (__attribute__((address_space(3))) void*)l, 16, 0, 0);
}

// ---------------------------------------------------------------------------
// prep_all (R7 granularity, mk is now a PURE STREAMING CAST — the [t][bh][cc]
// layout is kept; attn's DMA staging handles the row stride per-lane).
//   [0,3072)        prep_a   : Abf = bf16(x+pe)
//   [3072,6144)     wqkv^T   -> Wqkvt[3072][1024]
//   [6144,7168)     wout^T   -> Woutt[1024][1024]
//   [7168,19456)    mk       : flat fp32 -> bf16 cast (same layout)
//   [19456,22528)   mv       -> mv_t[bh][cc][t]
// ---------------------------------------------------------------------------
__device__ __forceinline__ void tr32(const float* __restrict__ in, u16* __restrict__ out,
                                     int R, int Cc, int r0, int c0, int tid, float* sm) {
    #pragma unroll
    for (int i = 0; i < 4; i++) {
        int r = i * 8 + (tid >> 5), c = tid & 31;
        sm[r * 33 + c] = in[(size_t)(r0 + r) * Cc + c0 + c];
    }
    __syncthreads();
    #pragma unroll
    for (int i = 0; i < 4; i++) {
        int cw = i * 8 + (tid >> 5), rw = tid & 31;
        out[(size_t)(c0 + cw) * R + r0 + rw] = f2bf(sm[rw * 33 + cw]);
    }
}

__global__ __launch_bounds__(256) void prep_all(
    const float* __restrict__ x, const float* __restrict__ pe, u16* __restrict__ Abf,
    const float* __restrict__ wqkv, u16* __restrict__ Wqkvt,
    const float* __restrict__ wout, u16* __restrict__ Woutt,
    const float* __restrict__ mk, u16* __restrict__ mk_bf,
    const float* __restrict__ mv, u16* __restrict__ mv_t)
{
    __shared__ float sm[64 * 65];
    const int bid = blockIdx.x, tid = threadIdx.x;

    if (bid < 3072) {                       // prep_a
        size_t i = ((size_t)bid * 256 + tid) * 4;
        float4 xv = *(const float4*)(x + i);
        float4 pv = *(const float4*)(pe + i);
        us4 o;
        o[0] = f2bf(xv.x + pv.x); o[1] = f2bf(xv.y + pv.y);
        o[2] = f2bf(xv.z + pv.z); o[3] = f2bf(xv.w + pv.w);
        *(us4*)(Abf + i) = o;
    } else if (bid < 6144) {                // wqkv transpose
        int b2 = bid - 3072;
        tr32(wqkv, Wqkvt, C_DIM, N3C, (b2 / 96) * 32, (b2 % 96) * 32, tid, sm);
    } else if (bid < 7168) {                // wout transpose
        int b3 = bid - 6144;
        tr32(wout, Woutt, C_DIM, C_DIM, (b3 / 32) * 32, (b3 % 32) * 32, tid, sm);
    } else if (bid < 19456) {               // mk: pure streaming fp32->bf16 cast
        int b4 = bid - 7168;
        size_t i = ((size_t)b4 * 256 + tid) * 4;
        float4 v = *(const float4*)(mk + i);
        us4 o;
        o[0] = f2bf(v.x); o[1] = f2bf(v.y); o[2] = f2bf(v.z); o[3] = f2bf(v.w);
        *(us4*)(mk_bf + i) = o;
    } else {                                // prep_mv (transpose to [bh][cc][t])
        int b5 = bid - 19456;
        int bh = b5 & 127;
        int t0 = (b5 >> 7) * 64;
        #pragma unroll
        for (int i = 0; i < 16; i++) {
            int r = i * 4 + (tid >> 6), c = tid & 63;
            sm[r * 65 + c] = mv[((size_t)(t0 + r) * 128 + bh) * 64 + c];
        }
        __syncthreads();
        #pragma unroll
        for (int i = 0; i < 16; i++) {
            int cc = i * 4 + (tid >> 6), tw = tid & 63;
            mv_t[((size_t)bh * 64 + cc) * M_DIM + t0 + tw] = f2bf(sm[tw * 65 + cc]);
        }
    }
}

// ---------------------------------------------------------------------------
// prep_vwt: Vw[bh][s][cc] bf16 -> Vwt[bh][cc][s] bf16
// ---------------------------------------------------------------------------
__global__ __launch_bounds__(256) void prep_vwt(
    const u16* __restrict__ Vw, u16* __restrict__ Vwt)
{
    __shared__ u16 tile[64][66];
    const int tid = threadIdx.x;
    const int bh = blockIdx.x & 127;
    const int t0 = (blockIdx.x >> 7) * 64;
    #pragma unroll
    for (int i = 0; i < 16; i++) {
        int r = i * 4 + (tid >> 6), c = tid & 63;
        tile[r][c] = Vw[((size_t)bh * S_DIM + t0 + r) * 64 + c];
    }
    __syncthreads();
    #pragma unroll
    for (int i = 0; i < 16; i++) {
        int cc = i * 4 + (tid >> 6), tw = tid & 63;
        Vwt[((size_t)bh * 64 + cc) * S_DIM + t0 + tw] = tile[tw][cc];
    }
}

// ---------------------------------------------------------------------------
// qkv GEMM: 128x64 tiles, BK=64, single-buffer swizzled DMA staging (R7) +
// LDS-TRANSPOSED EPILOGUE: acc -> bf16 Cs[128][72] -> us8 stores with 128-B
// row segments (replaces 32 scalar 2-B stores/thread = the hidden store wall).
// ---------------------------------------------------------------------------
__global__ __launch_bounds__(256) void qkv_gemm(
    const u16* __restrict__ Abf, const u16* __restrict__ Wt,
    const float* __restrict__ bias,
    u16* __restrict__ Qw, u16* __restrict__ Kw, u16* __restrict__ Vw)
{
    __shared__ u16 smem[128 * 64 + 64 * 64];   // As | Bs ; Cs aliases (needs 128*72)
    u16* As = smem;
    u16* Bs = smem + 128 * 64;
    u16* Cs = smem;                            // epilogue reuse (9216 u16 <= 12288)

    const int tid = threadIdx.x;
    const int lane = tid & 63, w = tid >> 6;
    const int lr = lane & 15, quad = lane >> 4;
    const int wm = w >> 1, wn = w & 1;
    const int row0 = blockIdx.y * 128, col0 = blockIdx.x * 64;

    f4v acc[4][2];
    #pragma unroll
    for (int i = 0; i < 4; i++)
        #pragma unroll
        for (int j = 0; j < 2; j++)
            acc[i][j] = (f4v){0.f, 0.f, 0.f, 0.f};

    for (int k0 = 0; k0 < C_DIM; k0 += 64) {
        __syncthreads();
        #pragma unroll
        for (int j = 0; j < 4; j++) {
            int idx = j * 256 + tid;
            int r = idx >> 3, c = (idx & 7) ^ (r & 7);
            gload16(&Abf[(size_t)(row0 + r) * C_DIM + k0 + c * 8], &As[idx * 8]);
        }
        #pragma unroll
        for (int j = 0; j < 2; j++) {
            int idx = j * 256 + tid;
            int r = idx >> 3, c = (idx & 7) ^ (r & 7);
            gload16(&Wt[(size_t)(col0 + r) * C_DIM + k0 + c * 8], &Bs[idx * 8]);
        }
        __syncthreads();
        #pragma unroll
        for (int kh = 0; kh < 2; kh++) {
            bf8v a[4], b[2];
            #pragma unroll
            for (int mi = 0; mi < 4; mi++) {
                int row = wm * 64 + mi * 16 + lr;
                int p = (kh * 4 + quad) ^ (lr & 7);
                a[mi] = *(const bf8v*)&As[row * 64 + p * 8];
            }
            #pragma unroll
            for (int nj = 0; nj < 2; nj++) {
                int row = wn * 32 + nj * 16 + lr;
                int p = (kh * 4 + quad) ^ (lr & 7);
                b[nj] = *(const bf8v*)&Bs[row * 64 + p * 8];
            }
            #pragma unroll
            for (int mi = 0; mi < 4; mi++)
                #pragma unroll
                for (int nj = 0; nj < 2; nj++)
                    acc[mi][nj] = __builtin_amdgcn_mfma_f32_16x16x32_bf16(a[mi], b[nj], acc[mi][nj], 0, 0, 0);
        }
    }

    // Epilogue: bias+scale -> bf16 -> LDS transpose -> coalesced us8 stores.
    // This block's 64-col band maps to exactly one (which, h).
    const int which = col0 >> 10;
    const int h = (col0 >> 6) & 15;
    const float qs = (which == 0) ? QSCALE : 1.0f;
    u16* dstbuf = (which == 0) ? Qw : ((which == 1) ? Kw : Vw);

    __syncthreads();   // all MFMA reads of As/Bs complete before Cs overwrite
    #pragma unroll
    for (int nj = 0; nj < 2; nj++) {
        int col = col0 + wn * 32 + nj * 16 + lr;
        float bv = bias[col];
        #pragma unroll
        for (int mi = 0; mi < 4; mi++)
            #pragma unroll
            for (int reg = 0; reg < 4; reg++)
                Cs[(wm * 64 + mi * 16 + quad * 4 + reg) * 72 + wn * 32 + nj * 16 + lr] =
                    f2bf((acc[mi][nj][reg] + bv) * qs);
    }
    __syncthreads();
    {
        int r = tid >> 1, half = tid & 1;
        int rg = row0 + r, s = rg >> 3, bb = rg & 7;
        u16* drow = dstbuf + ((size_t)(bb * 16 + h) * S_DIM + s) * 64 + half * 32;
        #pragma unroll
        for (int i = 0; i < 4; i++)
            *(us8*)(drow + i * 8) = *(const us8*)&Cs[r * 72 + half * 32 + i * 8];
    }
}

// ---------------------------------------------------------------------------
// attn_split: 64-key chunks, single-buffer swizzled DMA staging (R7 winner),
// P in registers, exp2 softmax, wave-uniform mask skip, mk read directly from
// [t][bh][cc] (stride handled per-lane by the DMA), LDS-transposed Op write.
// ---------------------------------------------------------------------------
__global__ __launch_bounds__(256) void attn_split(
    const u16* __restrict__ Qw, const u16* __restrict__ Kw,
    const u16* __restrict__ mk_bf, const u16* __restrict__ Vwt,
    const u16* __restrict__ mv_t, const unsigned char* __restrict__ terminal,
    const int* __restrict__ mem_len, u16* __restrict__ Op, float* __restrict__ ml)
{
    __shared__ u16 smem[2 * 64 * 64];   // Ks | Vs ; Os aliases Ks (needs 64*72)
    u16* Ks = smem;
    u16* Vs = smem + 64 * 64;
    u16* Os = smem;

    const int tid = threadIdx.x;
    const int lane = tid & 63, w = tid >> 6;
    const int lr = lane & 15, quad = lane >> 4, q8 = quad * 8;
    const int bid = blockIdx.x;
    const int split = bid & (NSPLIT - 1);
    const int g = bid / NSPLIT;                     // bhsc
    const int b = g & 7, h = (g >> 3) & 15, sc = g >> 7;
    const int bh = b * 16 + h, sq0 = sc * 64;
    const int L = terminal[b] ? 0 : mem_len[b];
    const int qrow = sq0 + w * 16 + lr;

    // Q as B-fragment (pre-scaled by QSCALE in qkv epilogue)
    const u16* qbase = Qw + ((size_t)bh * S_DIM + sq0 + w * 16 + lr) * 64;
    bf8v qf0 = *(const bf8v*)&qbase[q8];
    bf8v qf1 = *(const bf8v*)&qbase[32 + q8];

    f4v O[4];
    #pragma unroll
    for (int nj = 0; nj < 4; nj++) O[nj] = (f4v){0.f, 0.f, 0.f, 0.f};
    float m_i = -1e30f, l_i = 0.0f;

    const int memChunks = (L + 63) >> 6;
    const int total = memChunks + sc + 1;
    const int lo = (split * total) / NSPLIT;
    const int hi = ((split + 1) * total) / NSPLIT;

    const f4v zero = (f4v){0.f, 0.f, 0.f, 0.f};

    for (int ch = lo; ch < hi; ch++) {
        const bool isMem = (ch < memChunks);
        const int tloc = isMem ? ch * 64 : (ch - memChunks) * 64;
        const u16* kb; size_t kstr;
        if (isMem) { kb = mk_bf + ((size_t)tloc * 128 + bh) * 64; kstr = 128 * 64; }
        else       { kb = Kw + ((size_t)bh * S_DIM + tloc) * 64; kstr = 64; }
        const u16* vb; size_t vstr;
        if (isMem) { vb = mv_t + (size_t)bh * 64 * M_DIM + tloc; vstr = M_DIM; }
        else       { vb = Vwt + (size_t)bh * 64 * S_DIM + tloc; vstr = S_DIM; }

        __syncthreads();   // previous chunk's consumers done
        #pragma unroll
        for (int j = 0; j < 2; j++) {              // Ks: 64 rows x 8 chunks
            int idx = j * 256 + tid;
            int r = idx >> 3, c = (idx & 7) ^ (r & 7);
            gload16(kb + (size_t)r * kstr + c * 8, &Ks[idx * 8]);
        }
        #pragma unroll
        for (int j = 0; j < 2; j++) {              // Vs: 64 cc-rows x 8 chunks
            int idx = j * 256 + tid;
            int cc = idx >> 3, c = (idx & 7) ^ (cc & 7);
            gload16(vb + (size_t)cc * vstr + c * 8, &Vs[idx * 8]);
        }
        __syncthreads();

        // S^T tiles: sv[tt] covers t = tloc + tt*16 + quad*4 + reg, q = lane&15
        f4v sv[4];
        #pragma unroll
        for (int tt = 0; tt < 4; tt++) {
            int row = tt * 16 + lr;
            int p0 = quad ^ (lr & 7), p1 = (4 + quad) ^ (lr & 7);
            bf8v k0 = *(const bf8v*)&Ks[row * 64 + p0 * 8];
            bf8v k1 = *(const bf8v*)&Ks[row * 64 + p1 * 8];
            sv[tt] = __builtin_amdgcn_mfma_f32_16x16x32_bf16(k0, qf0, zero, 0, 0, 0);
            sv[tt] = __builtin_amdgcn_mfma_f32_16x16x32_bf16(k1, qf1, sv[tt], 0, 0, 0);
        }

        // Mask — wave-uniform skip (only boundary/diagonal chunks pay)
        if (isMem) {
            if (tloc + 64 > L) {
                #pragma unroll
                for (int tt = 0; tt < 4; tt++)
                    #pragma unroll
                    for (int reg = 0; reg < 4; reg++) {
                        int t = tloc + tt * 16 + quad * 4 + reg;
                        if (t >= L) sv[tt][reg] = -1e30f;
                    }
            }
        } else {
            if (tloc + 63 > sq0 + w * 16) {
                #pragma unroll
                for (int tt = 0; tt < 4; tt++)
                    #pragma unroll
                    for (int reg = 0; reg < 4; reg++) {
                        int t = tloc + tt * 16 + quad * 4 + reg;
                        if (t > qrow) sv[tt][reg] = -1e30f;
                    }
            }
        }

        // Online softmax in exp2 domain; reduce across lanes q, q+16, q+32, q+48
        float rowmax = fmaxf(fmaxf(sv[0][0], sv[0][1]), fmaxf(sv[0][2], sv[0][3]));
        #pragma unroll
        for (int tt = 1; tt < 4; tt++)
            rowmax = fmaxf(rowmax, fmaxf(fmaxf(sv[tt][0], sv[tt][1]),
                                         fmaxf(sv[tt][2], sv[tt][3])));
        rowmax = fmaxf(rowmax, __shfl_xor(rowmax, 16));
        rowmax = fmaxf(rowmax, __shfl_xor(rowmax, 32));
        float mnew = fmaxf(m_i, rowmax);
        float alpha = EX2(m_i - mnew);
        m_i = mnew;
        float sum = 0.0f;
        bf4v pf[4];
        #pragma unroll
        for (int tt = 0; tt < 4; tt++) {
            #pragma unroll
            for (int reg = 0; reg < 4; reg++) {
                float p = EX2(sv[tt][reg] - mnew);
                sum += p;
                pf[tt][reg] = (short)f2bf(p);
            }
        }
        sum += __shfl_xor(sum, 16);
        sum += __shfl_xor(sum, 32);
        l_i = l_i * alpha + sum;

        // Realign alpha to O-tile rows (O row q' = quad*4+reg; alpha at lane q')
        float alphaR[4];
        #pragma unroll
        for (int reg = 0; reg < 4; reg++)
            alphaR[reg] = __shfl(alpha, quad * 4 + reg);
        #pragma unroll
        for (int nj = 0; nj < 4; nj++)
            #pragma unroll
            for (int reg = 0; reg < 4; reg++)
                O[nj][reg] *= alphaR[reg];

        // PV: A = P (regs), B = V from Vs[cc][t] (de-swizzled bf4v reads)
        #pragma unroll
        for (int tt = 0; tt < 4; tt++) {
            #pragma unroll
            for (int nj = 0; nj < 4; nj++) {
                int cc = nj * 16 + lr;
                int c = (tt * 2 + (quad >> 1)) ^ (lr & 7);
                bf4v vf = *(const bf4v*)&Vs[cc * 64 + c * 8 + (quad & 1) * 4];
                O[nj] = mfma16x16x16bf16(pf[tt], vf, O[nj]);
            }
        }
    }

    // Write partials via LDS transpose (Os aliases Ks) for coalesced us8 stores
    const size_t pbase = (size_t)(g * NSPLIT + split) * 64;
    if (quad == 0) {
        int row = w * 16 + lr;
        float2 mlv = {m_i, l_i};
        *(float2*)&ml[(pbase + row) * 2] = mlv;
    }
    __syncthreads();   // all K/V consumers done before Os overwrite
    #pragma unroll
    for (int reg = 0; reg < 4; reg++)
        #pragma unroll
        for (int nj = 0; nj < 4; nj++)
            Os[(w * 16 + quad * 4 + reg) * 72 + nj * 16 + lr] = f2bf(O[nj][reg]);
    __syncthreads();
    {
        int row = tid >> 2, q4 = tid & 3;
        us8 v0 = *(const us8*)&Os[row * 72 + q4 * 16];
        us8 v1 = *(const us8*)&Os[row * 72 + q4 * 16 + 8];
        size_t ob = (pbase + row) * 64 + q4 * 16;
        *(us8*)&Op[ob] = v0;
        *(us8*)&Op[ob + 8] = v1;
    }
}

// ---------------------------------------------------------------------------
// attn_combine: merge NSPLIT partials -> Obf[row=s*8+b][h*64+cc] bf16
// ---------------------------------------------------------------------------
__global__ __launch_bounds__(256) void attn_combine(
    const u16* __restrict__ Op, const float* __restrict__ ml, u16* __restrict__ Obf)
{
    const int g = blockIdx.x;                       // bhsc
    const int b = g & 7, h = (g >> 3) & 15, sc = g >> 7;
    const int tid = threadIdx.x;
    const int row = tid >> 2, c0 = (tid & 3) * 16;

    float m[NSPLIT], lv[NSPLIT];
    #pragma unroll
    for (int j = 0; j < NSPLIT; j++) {
        size_t base = (size_t)(g * NSPLIT + j) * 64 + row;
        m[j]  = ml[base * 2];
        lv[j] = ml[base * 2 + 1];
    }
    float mstar = m[0];
    #pragma unroll
    for (int j = 1; j < NSPLIT; j++) mstar = fmaxf(mstar, m[j]);
    float sc_j[NSPLIT], l = 0.0f;
    #pragma unroll
    for (int j = 0; j < NSPLIT; j++) {
        sc_j[j] = EX2(m[j] - mstar);                // exp2 domain
        l += sc_j[j] * lv[j];
    }
    float inv = 1.0f / l;

    float o[16];
    #pragma unroll
    for (int c = 0; c < 16; c++) o[c] = 0.0f;
    #pragma unroll
    for (int j = 0; j < NSPLIT; j++) {
        const u16* src = &Op[((size_t)(g * NSPLIT + j) * 64 + row) * 64 + c0];
        us8 v0 = *(const us8*)src;
        us8 v1 = *(const us8*)(src + 8);
        #pragma unroll
        for (int c = 0; c < 8; c++) {
            o[c]     += sc_j[j] * bf2f(v0[c]);
            o[c + 8] += sc_j[j] * bf2f(v1[c]);
        }
    }
    int s = sc * 64 + row;
    size_t dst = ((size_t)s * 8 + b) * C_DIM + h * 64 + c0;
    us8 w0, w1;
    #pragma unroll
    for (int c = 0; c < 8; c++) {
        w0[c] = f2bf(o[c] * inv);
        w1[c] = f2bf(o[c + 8] * inv);
    }
    *(us8*)&Obf[dst] = w0;
    *(us8*)&Obf[dst + 8] = w1;
}

// ---------------------------------------------------------------------------
// proj GEMM: 128x64 tile (384 blocks), BK=64, single-buffer swizzled DMA (R7).
// fp32 dword stores already have 64-B segments — left as-is.
// ---------------------------------------------------------------------------
__global__ __launch_bounds__(256) void proj_gemm(
    const u16* __restrict__ Abf, const u16* __restrict__ Wt,
    const float* __restrict__ bias, float* __restrict__ out)
{
    __shared__ u16 As[128 * 64];
    __shared__ u16 Bs[64 * 64];
    const int tid = threadIdx.x;
    const int lane = tid & 63, w = tid >> 6;
    const int lr = lane & 15, quad = lane >> 4;
    const int wm = w >> 1, wn = w & 1;
    const int row0 = blockIdx.y * 128, col0 = blockIdx.x * 64;

    f4v acc[4][2];
    #pragma unroll
    for (int i = 0; i < 4; i++)
        #pragma unroll
        for (int j = 0; j < 2; j++)
            acc[i][j] = (f4v){0.f, 0.f, 0.f, 0.f};

    for (int k0 = 0; k0 < C_DIM; k0 += 64) {
        __syncthreads();
        #pragma unroll
        for (int j = 0; j < 4; j++) {
            int idx = j * 256 + tid;
            int r = idx >> 3, c = (idx & 7) ^ (r & 7);
            gload16(&Abf[(size_t)(row0 + r) * C_DIM + k0 + c * 8], &As[idx * 8]);
        }
        #pragma unroll
        for (int j = 0; j < 2; j++) {
            int idx = j * 256 + tid;
            int r = idx >> 3, c = (idx & 7) ^ (r & 7);
            gload16(&Wt[(size_t)(col0 + r) * C_DIM + k0 + c * 8], &Bs[idx * 8]);
        }
        __syncthreads();
        #pragma unroll
        for (int kh = 0; kh < 2; kh++) {
            bf8v a[4], b[2];
            #pragma unroll
            for (int mi = 0; mi < 4; mi++) {
                int row = wm * 64 + mi * 16 + lr;
                int p = (kh * 4 + quad) ^ (lr & 7);
                a[mi] = *(const bf8v*)&As[row * 64 + p * 8];
            }
            #pragma unroll
            for (int nj = 0; nj < 2; nj++) {
                int row = wn * 32 + nj * 16 + lr;
                int p = (kh * 4 + quad) ^ (lr & 7);
                b[nj] = *(const bf8v*)&Bs[row * 64 + p * 8];
            }
            #pragma unroll
            for (int mi = 0; mi < 4; mi++)
                #pragma unroll
                for (int nj = 0; nj < 2; nj++)
                    acc[mi][nj] = __builtin_amdgcn_mfma_f32_16x16x32_bf16(a[mi], b[nj], acc[mi][nj], 0, 0, 0);
        }
    }

    #pragma unroll
    for (int nj = 0; nj < 2; nj++) {
        int col = col0 + wn * 32 + nj * 16 + lr;
        float bv = bias[col];
        #pragma unroll
        for (int mi = 0; mi < 4; mi++) {
            #pragma unroll
            for (int reg = 0; reg < 4; reg++) {
                int rg = row0 + wm * 64 + mi * 16 + quad * 4 + reg;
                out[(size_t)rg * C_DIM + col] = acc[mi][nj][reg] + bv;
            }
        }
    }
}

// ---------------------------------------------------------------------------
extern "C" void kernel_launch(void* const* d_in, const int* in_sizes, int n_in,
                              void* d_out, int out_size, void* d_ws, size_t ws_size,
                              hipStream_t stream) {
    const float* x    = (const float*)d_in[0];
    const float* pe   = (const float*)d_in[1];
    const float* mk   = (const float*)d_in[2];
    const float* mv   = (const float*)d_in[3];
    const float* wqkv = (const float*)d_in[4];
    const float* bqkv = (const float*)d_in[5];
    const float* wout = (const float*)d_in[6];
    const float* bout = (const float*)d_in[7];
    const unsigned char* term = (const unsigned char*)d_in[8];
    // d_in[9] content_mask (causal, analytic), d_in[10] padding_mask (all False)
    const int* mem_len = (const int*)d_in[11];

    char* ws = (char*)d_ws;
    u16* Abf   = (u16*)(ws + 0);          // 6291456 B  (Obf aliases after qkv)
    u16* Obf   = (u16*)(ws + 0);
    u16* Wqkvt = (u16*)(ws + 6291456);    // 6291456 B  (Vwt aliases after qkv)
    u16* Vwt   = (u16*)(ws + 6291456);
    u16* Woutt = (u16*)(ws + 12582912);   // 2097152 B
    u16* mk_bf = (u16*)(ws + 14680064);   // 25165824 B  [t][bh][cc] bf16 (cast only)
    u16* mv_t  = (u16*)(ws + 39845888);   // 25165824 B  [bh][cc][t]
    u16* Qw    = (u16*)(ws + 65011712);   // 6291456 B
    u16* Kw    = (u16*)(ws + 71303168);   // 6291456 B
    u16* Vw    = (u16*)(ws + 77594624);   // 6291456 B
    u16* Op    = (u16*)(ws + 83886080);   // 25165824 B (768*4*64*64 bf16)
    float* ml  = (float*)(ws + 109051904);// 1572864 B  end 110624768

    float* out = (float*)d_out;

    prep_all<<<22528, 256, 0, stream>>>(x, pe, Abf, wqkv, Wqkvt, wout, Woutt,
                                        mk, mk_bf, mv, mv_t);

    qkv_gemm<<<dim3(N3C / 64, ROWS / 128), 256, 0, stream>>>(
        Abf, Wqkvt, bqkv, Qw, Kw, Vw);

    prep_vwt<<<(S_DIM / 64) * 128, 256, 0, stream>>>(Vw, Vwt);

    attn_split<<<B_DIM * H_DIM * (S_DIM / 64) * NSPLIT, 256, 0, stream>>>(
        Qw, Kw, mk_bf, Vwt, mv_t, term, mem_len, Op, ml);

    attn_combine<<<B_DIM * H_DIM * (S_DIM / 64), 256, 0, stream>>>(Op, ml, Obf);

    proj_gemm<<<dim3(C_DIM / 64, ROWS / 128), 256, 0, stream>>>(
        Obf, Woutt, bout, out);
}

// Round 10
// 287.195 us; speedup vs baseline: 1.0581x; 1.0558x over previous
//
#include <hip/hip_runtime.h>
#include <math.h>

// Problem constants
#define S_DIM 384
#define B_DIM 8
#define C_DIM 1024
#define H_DIM 16
#define M_DIM 1536
#define CC_DIM 64
#define ROWS  (S_DIM * B_DIM)      // 3072
#define N3C   (3 * C_DIM)          // 3072
#define CHUNK 6                    // chunks per attention split-block
#define MAXS  5                    // max splits per (b,h,sc):  ceil(30/6)=5

typedef unsigned short u16;
typedef short bf8v  __attribute__((ext_vector_type(8)));   // 8 bf16 (bit pattern)
typedef short bf4v  __attribute__((ext_vector_type(4)));   // 4 bf16
typedef u16   us8   __attribute__((ext_vector_type(8)));
typedef u16   us4   __attribute__((ext_vector_type(4)));
typedef float f4v   __attribute__((ext_vector_type(4)));

__device__ __forceinline__ u16 f2bf(float f) {
    unsigned u = __float_as_uint(f);
    u += 0x7fffu + ((u >> 16) & 1u);     // round-to-nearest-even
    return (u16)(u >> 16);
}
__device__ __forceinline__ float bf2f(u16 v) {
    return __uint_as_float(((unsigned)v) << 16);
}
#if __has_builtin(__builtin_amdgcn_exp2f)
#define EX2(x) __builtin_amdgcn_exp2f(x)
#else
#define EX2(x) __expf((x) * 0.69314718056f)
#endif
#define QSCALE (0.125f * 1.44269504f)    // 1/sqrt(64) * log2(e): softmax in exp2 domain

// MFMA 16x16x16 bf16 wrapper: builtin exists in the DEVICE pass (HW-verified
// rounds 4/6/7) but __has_builtin is false in the HOST pass — host needs a body.
__device__ __forceinline__ f4v mfma16x16x16bf16(bf4v a, bf4v b, f4v c) {
#if __has_builtin(__builtin_amdgcn_mfma_f32_16x16x16bf16_1k)
    return __builtin_amdgcn_mfma_f32_16x16x16bf16_1k(a, b, c, 0, 0, 0);
#else
    return c;   // host-pass placeholder; never executed on device
#endif
}

// async global->LDS, 16B per lane; lds dest must be wave-contiguous (base+lane*16)
__device__ __forceinline__ void gload16(const u16* g, u16* l) {
    __builtin_amdgcn_global_load_lds(
        (const __attribute__((address_space(1))) void*)g,
        (__attribute__((address_space(3))) void*)l, 16, 0, 0);
}

// ---------------------------------------------------------------------------
// prep_all: merged preps. Cast regions do 2 independent float4s per thread
// (double the outstanding loads per wave). Block ranges:
//   [0,1536)        prep_a   : Abf = bf16(x+pe), 2048 elts/block
//   [1536,4608)     wqkv^T   -> Wqkvt[3072][1024]
//   [4608,5632)     wout^T   -> Woutt[1024][1024]
//   [5632,11776)    mk       : flat fp32 -> bf16 cast (layout kept [t][bh][cc])
//   [11776,14848)   mv       -> mv_t[bh][cc][t]
// ---------------------------------------------------------------------------
__device__ __forceinline__ void tr32(const float* __restrict__ in, u16* __restrict__ out,
                                     int R, int Cc, int r0, int c0, int tid, float* sm) {
    #pragma unroll
    for (int i = 0; i < 4; i++) {
        int r = i * 8 + (tid >> 5), c = tid & 31;
        sm[r * 33 + c] = in[(size_t)(r0 + r) * Cc + c0 + c];
    }
    __syncthreads();
    #pragma unroll
    for (int i = 0; i < 4; i++) {
        int cw = i * 8 + (tid >> 5), rw = tid & 31;
        out[(size_t)(c0 + cw) * R + r0 + rw] = f2bf(sm[rw * 33 + cw]);
    }
}

__global__ __launch_bounds__(256) void prep_all(
    const float* __restrict__ x, const float* __restrict__ pe, u16* __restrict__ Abf,
    const float* __restrict__ wqkv, u16* __restrict__ Wqkvt,
    const float* __restrict__ wout, u16* __restrict__ Woutt,
    const float* __restrict__ mk, u16* __restrict__ mk_bf,
    const float* __restrict__ mv, u16* __restrict__ mv_t)
{
    __shared__ float sm[64 * 65];
    const int bid = blockIdx.x, tid = threadIdx.x;

    if (bid < 1536) {                       // prep_a: 2 indep float4s/thread
        size_t i0 = (size_t)bid * 2048 + tid * 4;
        #pragma unroll
        for (int j = 0; j < 2; j++) {
            size_t i = i0 + j * 1024;
            float4 xv = *(const float4*)(x + i);
            float4 pv = *(const float4*)(pe + i);
            us4 o;
            o[0] = f2bf(xv.x + pv.x); o[1] = f2bf(xv.y + pv.y);
            o[2] = f2bf(xv.z + pv.z); o[3] = f2bf(xv.w + pv.w);
            *(us4*)(Abf + i) = o;
        }
    } else if (bid < 4608) {                // wqkv transpose
        int b2 = bid - 1536;
        tr32(wqkv, Wqkvt, C_DIM, N3C, (b2 / 96) * 32, (b2 % 96) * 32, tid, sm);
    } else if (bid < 5632) {                // wout transpose
        int b3 = bid - 4608;
        tr32(wout, Woutt, C_DIM, C_DIM, (b3 / 32) * 32, (b3 % 32) * 32, tid, sm);
    } else if (bid < 11776) {               // mk: streaming cast, 2 float4s/thread
        size_t i0 = (size_t)(bid - 5632) * 2048 + tid * 4;
        #pragma unroll
        for (int j = 0; j < 2; j++) {
            size_t i = i0 + j * 1024;
            float4 v = *(const float4*)(mk + i);
            us4 o;
            o[0] = f2bf(v.x); o[1] = f2bf(v.y); o[2] = f2bf(v.z); o[3] = f2bf(v.w);
            *(us4*)(mk_bf + i) = o;
        }
    } else {                                // prep_mv (transpose to [bh][cc][t])
        int b5 = bid - 11776;
        int bh = b5 & 127;
        int t0 = (b5 >> 7) * 64;
        #pragma unroll
        for (int i = 0; i < 16; i++) {
            int r = i * 4 + (tid >> 6), c = tid & 63;
            sm[r * 65 + c] = mv[((size_t)(t0 + r) * 128 + bh) * 64 + c];
        }
        __syncthreads();
        #pragma unroll
        for (int i = 0; i < 16; i++) {
            int cc = i * 4 + (tid >> 6), tw = tid & 63;
            mv_t[((size_t)bh * 64 + cc) * M_DIM + t0 + tw] = f2bf(sm[tw * 65 + cc]);
        }
    }
}

// ---------------------------------------------------------------------------
// qkv GEMM: 128x64 tiles, BK=64, swizzled DMA staging, LDS-transposed
// epilogue. Q/K bands: coalesced us8 row stores. V band: stores DIRECTLY
// TRANSPOSED to Vwt[bh][cc][s] (prep_vwt kernel eliminated).
// ---------------------------------------------------------------------------
__global__ __launch_bounds__(256) void qkv_gemm(
    const u16* __restrict__ Abf, const u16* __restrict__ Wt,
    const float* __restrict__ bias,
    u16* __restrict__ Qw, u16* __restrict__ Kw, u16* __restrict__ Vwt)
{
    __shared__ u16 smem[128 * 64 + 64 * 64];   // As | Bs ; Cs aliases (128*72)
    u16* As = smem;
    u16* Bs = smem + 128 * 64;
    u16* Cs = smem;

    const int tid = threadIdx.x;
    const int lane = tid & 63, w = tid >> 6;
    const int lr = lane & 15, quad = lane >> 4;
    const int wm = w >> 1, wn = w & 1;
    const int row0 = blockIdx.y * 128, col0 = blockIdx.x * 64;

    f4v acc[4][2];
    #pragma unroll
    for (int i = 0; i < 4; i++)
        #pragma unroll
        for (int j = 0; j < 2; j++)
            acc[i][j] = (f4v){0.f, 0.f, 0.f, 0.f};

    for (int k0 = 0; k0 < C_DIM; k0 += 64) {
        __syncthreads();
        #pragma unroll
        for (int j = 0; j < 4; j++) {
            int idx = j * 256 + tid;
            int r = idx >> 3, c = (idx & 7) ^ (r & 7);
            gload16(&Abf[(size_t)(row0 + r) * C_DIM + k0 + c * 8], &As[idx * 8]);
        }
        #pragma unroll
        for (int j = 0; j < 2; j++) {
            int idx = j * 256 + tid;
            int r = idx >> 3, c = (idx & 7) ^ (r & 7);
            gload16(&Wt[(size_t)(col0 + r) * C_DIM + k0 + c * 8], &Bs[idx * 8]);
        }
        __syncthreads();
        #pragma unroll
        for (int kh = 0; kh < 2; kh++) {
            bf8v a[4], b[2];
            #pragma unroll
            for (int mi = 0; mi < 4; mi++) {
                int row = wm * 64 + mi * 16 + lr;
                int p = (kh * 4 + quad) ^ (lr & 7);
                a[mi] = *(const bf8v*)&As[row * 64 + p * 8];
            }
            #pragma unroll
            for (int nj = 0; nj < 2; nj++) {
                int row = wn * 32 + nj * 16 + lr;
                int p = (kh * 4 + quad) ^ (lr & 7);
                b[nj] = *(const bf8v*)&Bs[row * 64 + p * 8];
            }
            #pragma unroll
            for (int mi = 0; mi < 4; mi++)
                #pragma unroll
                for (int nj = 0; nj < 2; nj++)
                    acc[mi][nj] = __builtin_amdgcn_mfma_f32_16x16x32_bf16(a[mi], b[nj], acc[mi][nj], 0, 0, 0);
        }
    }

    const int which = col0 >> 10;
    const int h = (col0 >> 6) & 15;
    const float qs = (which == 0) ? QSCALE : 1.0f;

    __syncthreads();   // MFMA reads of As/Bs complete before Cs overwrite
    #pragma unroll
    for (int nj = 0; nj < 2; nj++) {
        int col = col0 + wn * 32 + nj * 16 + lr;
        float bv = bias[col];
        #pragma unroll
        for (int mi = 0; mi < 4; mi++)
            #pragma unroll
            for (int reg = 0; reg < 4; reg++)
                Cs[(wm * 64 + mi * 16 + quad * 4 + reg) * 72 + wn * 32 + nj * 16 + lr] =
                    f2bf((acc[mi][nj][reg] + bv) * qs);
    }
    __syncthreads();

    if (which != 2) {
        // Q/K: coalesced row stores to [bh][s][cc]
        u16* dstbuf = (which == 0) ? Qw : Kw;
        int r = tid >> 1, half = tid & 1;
        int rg = row0 + r, s = rg >> 3, bb = rg & 7;
        u16* drow = dstbuf + ((size_t)(bb * 16 + h) * S_DIM + s) * 64 + half * 32;
        #pragma unroll
        for (int i = 0; i < 4; i++)
            *(us8*)(drow + i * 8) = *(const us8*)&Cs[r * 72 + half * 32 + i * 8];
    } else {
        // V: transposed stores to Vwt[bh][cc][s] (s-contiguous us8 pairs)
        int cc = tid & 63, w4 = tid >> 6;
        int s0 = row0 >> 3;
        #pragma unroll
        for (int pb = 0; pb < 2; pb++) {
            int bb = w4 * 2 + pb;
            us8 v0, v1;
            #pragma unroll
            for (int sl = 0; sl < 8; sl++) {
                v0[sl] = Cs[(sl * 8 + bb) * 72 + cc];
                v1[sl] = Cs[((sl + 8) * 8 + bb) * 72 + cc];
            }
            u16* dr = Vwt + ((size_t)(bb * 16 + h) * 64 + cc) * S_DIM + s0;
            *(us8*)dr = v0;
            *(us8*)(dr + 8) = v1;
        }
    }
}

// ---------------------------------------------------------------------------
// attn_split: EQUAL-WORK split — block (g, j) processes chunks
// [j*CHUNK, min(j*CHUNK+CHUNK, total_g)). Every active block <= 6 chunks;
// inactive blocks exit. 64-key chunks, swizzled DMA staging, P in registers,
// exp2 softmax, wave-uniform mask skip, scalar partial writes (R7 form).
// ---------------------------------------------------------------------------
__global__ __launch_bounds__(256) void attn_split(
    const u16* __restrict__ Qw, const u16* __restrict__ Kw,
    const u16* __restrict__ mk_bf, const u16* __restrict__ Vwt,
    const u16* __restrict__ mv_t, const unsigned char* __restrict__ terminal,
    const int* __restrict__ mem_len, u16* __restrict__ Op, float* __restrict__ ml)
{
    __shared__ u16 Ks[64 * 64];   // [t][cc], chunk-swizzled
    __shared__ u16 Vs[64 * 64];   // [cc][t], chunk-swizzled

    const int tid = threadIdx.x;
    const int lane = tid & 63, w = tid >> 6;
    const int lr = lane & 15, quad = lane >> 4, q8 = quad * 8;
    const int bid = blockIdx.x;
    const int j = bid % MAXS;
    const int g = bid / MAXS;                       // bhsc
    const int b = g & 7, h = (g >> 3) & 15, sc = g >> 7;
    const int bh = b * 16 + h, sq0 = sc * 64;
    const int L = terminal[b] ? 0 : mem_len[b];
    const int memChunks = (L + 63) >> 6;
    const int total = memChunks + sc + 1;
    const int lo = j * CHUNK;
    const int hi = (lo + CHUNK < total) ? lo + CHUNK : total;
    if (lo >= total) return;                        // inactive slot

    const int qrow = sq0 + w * 16 + lr;

    // Q as B-fragment (pre-scaled by QSCALE in qkv epilogue)
    const u16* qbase = Qw + ((size_t)bh * S_DIM + sq0 + w * 16 + lr) * 64;
    bf8v qf0 = *(const bf8v*)&qbase[q8];
    bf8v qf1 = *(const bf8v*)&qbase[32 + q8];

    f4v O[4];
    #pragma unroll
    for (int nj = 0; nj < 4; nj++) O[nj] = (f4v){0.f, 0.f, 0.f, 0.f};
    float m_i = -1e30f, l_i = 0.0f;

    const f4v zero = (f4v){0.f, 0.f, 0.f, 0.f};

    for (int ch = lo; ch < hi; ch++) {
        const bool isMem = (ch < memChunks);
        const int tloc = isMem ? ch * 64 : (ch - memChunks) * 64;
        const u16* kb; size_t kstr;
        if (isMem) { kb = mk_bf + ((size_t)tloc * 128 + bh) * 64; kstr = 128 * 64; }
        else       { kb = Kw + ((size_t)bh * S_DIM + tloc) * 64; kstr = 64; }
        const u16* vb; size_t vstr;
        if (isMem) { vb = mv_t + (size_t)bh * 64 * M_DIM + tloc; vstr = M_DIM; }
        else       { vb = Vwt + (size_t)bh * 64 * S_DIM + tloc; vstr = S_DIM; }

        __syncthreads();   // previous chunk's consumers done
        #pragma unroll
        for (int jj = 0; jj < 2; jj++) {           // Ks: 64 rows x 8 chunks
            int idx = jj * 256 + tid;
            int r = idx >> 3, c = (idx & 7) ^ (r & 7);
            gload16(kb + (size_t)r * kstr + c * 8, &Ks[idx * 8]);
        }
        #pragma unroll
        for (int jj = 0; jj < 2; jj++) {           // Vs: 64 cc-rows x 8 chunks
            int idx = jj * 256 + tid;
            int cc = idx >> 3, c = (idx & 7) ^ (cc & 7);
            gload16(vb + (size_t)cc * vstr + c * 8, &Vs[idx * 8]);
        }
        __syncthreads();

        // S^T tiles: sv[tt] covers t = tloc + tt*16 + quad*4 + reg, q = lane&15
        f4v sv[4];
        #pragma unroll
        for (int tt = 0; tt < 4; tt++) {
            int row = tt * 16 + lr;
            int p0 = quad ^ (lr & 7), p1 = (4 + quad) ^ (lr & 7);
            bf8v k0 = *(const bf8v*)&Ks[row * 64 + p0 * 8];
            bf8v k1 = *(const bf8v*)&Ks[row * 64 + p1 * 8];
            sv[tt] = __builtin_amdgcn_mfma_f32_16x16x32_bf16(k0, qf0, zero, 0, 0, 0);
            sv[tt] = __builtin_amdgcn_mfma_f32_16x16x32_bf16(k1, qf1, sv[tt], 0, 0, 0);
        }

        // Mask — wave-uniform skip (only boundary/diagonal chunks pay)
        if (isMem) {
            if (tloc + 64 > L) {
                #pragma unroll
                for (int tt = 0; tt < 4; tt++)
                    #pragma unroll
                    for (int reg = 0; reg < 4; reg++) {
                        int t = tloc + tt * 16 + quad * 4 + reg;
                        if (t >= L) sv[tt][reg] = -1e30f;
                    }
            }
        } else {
            if (tloc + 63 > sq0 + w * 16) {
                #pragma unroll
                for (int tt = 0; tt < 4; tt++)
                    #pragma unroll
                    for (int reg = 0; reg < 4; reg++) {
                        int t = tloc + tt * 16 + quad * 4 + reg;
                        if (t > qrow) sv[tt][reg] = -1e30f;
                    }
            }
        }

        // Online softmax in exp2 domain; reduce across lanes q, q+16, q+32, q+48
        float rowmax = fmaxf(fmaxf(sv[0][0], sv[0][1]), fmaxf(sv[0][2], sv[0][3]));
        #pragma unroll
        for (int tt = 1; tt < 4; tt++)
            rowmax = fmaxf(rowmax, fmaxf(fmaxf(sv[tt][0], sv[tt][1]),
                                         fmaxf(sv[tt][2], sv[tt][3])));
        rowmax = fmaxf(rowmax, __shfl_xor(rowmax, 16));
        rowmax = fmaxf(rowmax, __shfl_xor(rowmax, 32));
        float mnew = fmaxf(m_i, rowmax);
        float alpha = EX2(m_i - mnew);
        m_i = mnew;
        float sum = 0.0f;
        bf4v pf[4];
        #pragma unroll
        for (int tt = 0; tt < 4; tt++) {
            #pragma unroll
            for (int reg = 0; reg < 4; reg++) {
                float p = EX2(sv[tt][reg] - mnew);
                sum += p;
                pf[tt][reg] = (short)f2bf(p);
            }
        }
        sum += __shfl_xor(sum, 16);
        sum += __shfl_xor(sum, 32);
        l_i = l_i * alpha + sum;

        // Realign alpha to O-tile rows (O row q' = quad*4+reg; alpha at lane q')
        float alphaR[4];
        #pragma unroll
        for (int reg = 0; reg < 4; reg++)
            alphaR[reg] = __shfl(alpha, quad * 4 + reg);
        #pragma unroll
        for (int nj = 0; nj < 4; nj++)
            #pragma unroll
            for (int reg = 0; reg < 4; reg++)
                O[nj][reg] *= alphaR[reg];

        // PV: A = P (regs), B = V from Vs[cc][t] (de-swizzled bf4v reads)
        #pragma unroll
        for (int tt = 0; tt < 4; tt++) {
            #pragma unroll
            for (int nj = 0; nj < 4; nj++) {
                int cc = nj * 16 + lr;
                int c = (tt * 2 + (quad >> 1)) ^ (lr & 7);
                bf4v vf = *(const bf4v*)&Vs[cc * 64 + c * 8 + (quad & 1) * 4];
                O[nj] = mfma16x16x16bf16(pf[tt], vf, O[nj]);
            }
        }
    }

    // Write partials (unnormalized O, m, l) — slot (g, j)
    const size_t pbase = (size_t)(g * MAXS + j) * 64;
    if (quad == 0) {
        int row = w * 16 + lr;
        float2 mlv = {m_i, l_i};
        *(float2*)&ml[(pbase + row) * 2] = mlv;
    }
    #pragma unroll
    for (int reg = 0; reg < 4; reg++) {
        int row = w * 16 + quad * 4 + reg;
        #pragma unroll
        for (int nj = 0; nj < 4; nj++)
            Op[(pbase + row) * 64 + nj * 16 + lr] = f2bf(O[nj][reg]);
    }
}

// ---------------------------------------------------------------------------
// attn_combine: merge the valid slots (j*CHUNK < total_g) -> Obf bf16
// ---------------------------------------------------------------------------
__global__ __launch_bounds__(256) void attn_combine(
    const unsigned char* __restrict__ terminal, const int* __restrict__ mem_len,
    const u16* __restrict__ Op, const float* __restrict__ ml, u16* __restrict__ Obf)
{
    const int g = blockIdx.x;                       // bhsc
    const int b = g & 7, h = (g >> 3) & 15, sc = g >> 7;
    const int tid = threadIdx.x;
    const int row = tid >> 2, c0 = (tid & 3) * 16;

    const int L = terminal[b] ? 0 : mem_len[b];
    const int total = ((L + 63) >> 6) + sc + 1;
    const int nsp = (total + CHUNK - 1) / CHUNK;    // valid slots

    float m[MAXS], lv[MAXS];
    #pragma unroll
    for (int j = 0; j < MAXS; j++) {
        if (j < nsp) {
            size_t base = (size_t)(g * MAXS + j) * 64 + row;
            m[j]  = ml[base * 2];
            lv[j] = ml[base * 2 + 1];
        } else { m[j] = -1e30f; lv[j] = 0.0f; }
    }
    float mstar = m[0];
    #pragma unroll
    for (int j = 1; j < MAXS; j++) mstar = fmaxf(mstar, m[j]);
    float sc_j[MAXS], l = 0.0f;
    #pragma unroll
    for (int j = 0; j < MAXS; j++) {
        sc_j[j] = (j < nsp) ? EX2(m[j] - mstar) : 0.0f;   // exp2 domain
        l += sc_j[j] * lv[j];
    }
    float inv = 1.0f / l;

    float o[16];
    #pragma unroll
    for (int c = 0; c < 16; c++) o[c] = 0.0f;
    for (int j = 0; j < nsp; j++) {
        const u16* src = &Op[((size_t)(g * MAXS + j) * 64 + row) * 64 + c0];
        us8 v0 = *(const us8*)src;
        us8 v1 = *(const us8*)(src + 8);
        #pragma unroll
        for (int c = 0; c < 8; c++) {
            o[c]     += sc_j[j] * bf2f(v0[c]);
            o[c + 8] += sc_j[j] * bf2f(v1[c]);
        }
    }
    int s = sc * 64 + row;
    size_t dst = ((size_t)s * 8 + b) * C_DIM + h * 64 + c0;
    us8 w0, w1;
    #pragma unroll
    for (int c = 0; c < 8; c++) {
        w0[c] = f2bf(o[c] * inv);
        w1[c] = f2bf(o[c + 8] * inv);
    }
    *(us8*)&Obf[dst] = w0;
    *(us8*)&Obf[dst + 8] = w1;
}

// ---------------------------------------------------------------------------
// proj GEMM: 64x64 tiles (768 blocks — fixes 1.5 block/CU tail), BK=64,
// swizzled DMA staging. Wave w handles rows w*16..w*16+15, all 64 cols.
// ---------------------------------------------------------------------------
__global__ __launch_bounds__(256) void proj_gemm(
    const u16* __restrict__ Abf, const u16* __restrict__ Wt,
    const float* __restrict__ bias, float* __restrict__ out)
{
    __shared__ u16 As[64 * 64];
    __shared__ u16 Bs[64 * 64];
    const int tid = threadIdx.x;
    const int lane = tid & 63, w = tid >> 6;
    const int lr = lane & 15, quad = lane >> 4;
    const int row0 = blockIdx.y * 64, col0 = blockIdx.x * 64;

    f4v acc[4];
    #pragma unroll
    for (int i = 0; i < 4; i++) acc[i] = (f4v){0.f, 0.f, 0.f, 0.f};

    for (int k0 = 0; k0 < C_DIM; k0 += 64) {
        __syncthreads();
        #pragma unroll
        for (int j = 0; j < 2; j++) {
            int idx = j * 256 + tid;
            int r = idx >> 3, c = (idx & 7) ^ (r & 7);
            gload16(&Abf[(size_t)(row0 + r) * C_DIM + k0 + c * 8], &As[idx * 8]);
            gload16(&Wt[(size_t)(col0 + r) * C_DIM + k0 + c * 8], &Bs[idx * 8]);
        }
        __syncthreads();
        #pragma unroll
        for (int kh = 0; kh < 2; kh++) {
            int p = (kh * 4 + quad) ^ (lr & 7);
            bf8v a = *(const bf8v*)&As[(w * 16 + lr) * 64 + p * 8];
            #pragma unroll
            for (int nj = 0; nj < 4; nj++) {
                bf8v bfr = *(const bf8v*)&Bs[(nj * 16 + lr) * 64 + p * 8];
                acc[nj] = __builtin_amdgcn_mfma_f32_16x16x32_bf16(a, bfr, acc[nj], 0, 0, 0);
            }
        }
    }

    #pragma unroll
    for (int nj = 0; nj < 4; nj++) {
        int col = col0 + nj * 16 + lr;
        float bv = bias[col];
        #pragma unroll
        for (int reg = 0; reg < 4; reg++) {
            int rg = row0 + w * 16 + quad * 4 + reg;
            out[(size_t)rg * C_DIM + col] = acc[nj][reg] + bv;
        }
    }
}

// ---------------------------------------------------------------------------
extern "C" void kernel_launch(void* const* d_in, const int* in_sizes, int n_in,
                              void* d_out, int out_size, void* d_ws, size_t ws_size,
                              hipStream_t stream) {
    const float* x    = (const float*)d_in[0];
    const float* pe   = (const float*)d_in[1];
    const float* mk   = (const float*)d_in[2];
    const float* mv   = (const float*)d_in[3];
    const float* wqkv = (const float*)d_in[4];
    const float* bqkv = (const float*)d_in[5];
    const float* wout = (const float*)d_in[6];
    const float* bout = (const float*)d_in[7];
    const unsigned char* term = (const unsigned char*)d_in[8];
    // d_in[9] content_mask (causal, analytic), d_in[10] padding_mask (all False)
    const int* mem_len = (const int*)d_in[11];

    char* ws = (char*)d_ws;
    u16* Abf   = (u16*)(ws + 0);          // 6291456 B  (Obf aliases after qkv)
    u16* Obf   = (u16*)(ws + 0);
    u16* Wqkvt = (u16*)(ws + 6291456);    // 6291456 B  (ml aliases after qkv)
    float* ml  = (float*)(ws + 6291456);  // 1966080 B  (768*5*64*2 f32)
    u16* Woutt = (u16*)(ws + 12582912);   // 2097152 B
    u16* mk_bf = (u16*)(ws + 14680064);   // 25165824 B  [t][bh][cc] bf16 (cast only)
    u16* mv_t  = (u16*)(ws + 39845888);   // 25165824 B  [bh][cc][t]
    u16* Qw    = (u16*)(ws + 65011712);   // 6291456 B
    u16* Kw    = (u16*)(ws + 71303168);   // 6291456 B
    u16* Vwt   = (u16*)(ws + 77594624);   // 6291456 B  [bh][cc][s] (written by qkv)
    u16* Op    = (u16*)(ws + 83886080);   // 31457280 B (768*5*64*64 bf16) end 115343360

    float* out = (float*)d_out;

    prep_all<<<14848, 256, 0, stream>>>(x, pe, Abf, wqkv, Wqkvt, wout, Woutt,
                                        mk, mk_bf, mv, mv_t);

    qkv_gemm<<<dim3(N3C / 64, ROWS / 128), 256, 0, stream>>>(
        Abf, Wqkvt, bqkv, Qw, Kw, Vwt);

    attn_split<<<B_DIM * H_DIM * (S_DIM / 64) * MAXS, 256, 0, stream>>>(
        Qw, Kw, mk_bf, Vwt, mv_t, term, mem_len, Op, ml);

    attn_combine<<<B_DIM * H_DIM * (S_DIM / 64), 256, 0, stream>>>(
        term, mem_len, Op, ml, Obf);

    proj_gemm<<<dim3(C_DIM / 64, ROWS / 64), 256, 0, stream>>>(
        Obf, Woutt, bout, out);
}